// Round 2
// baseline (532.769 us; speedup 1.0000x reference)
//
#include <hip/hip_runtime.h>
#include <cstdint>

#define MUL0 16
#define MUL1 8
#define NRBF 8
#define HID 64
#define WNUM 576
#define CUTOFF 5.0f
#define EPSF 1e-8f

#define INV_SQRT3 0.57735026918962576f
#define A_PATH    0.20412414523193154f   /* 1/sqrt(24) */
#define Q16       0.25f                  /* 1/sqrt(16) */
#define Q8        0.35355339059327373f   /* 1/sqrt(8)  */
#define PI_OVER_CUT 0.62831853071795865f /* pi/5 */

typedef _Float16 f16;
typedef _Float16 f16x8 __attribute__((ext_vector_type(8)));
typedef float f32x4 __attribute__((ext_vector_type(4)));

__device__ __forceinline__ float sigm(float x) { return 1.0f / (1.0f + __expf(-x)); }

// ---------------- prep: w_r2 (64 x 576 f32) -> W2T (576 x 64 f16) ----------------
extern "C" __global__ __launch_bounds__(256) void k_prep_w2t(
    const float* __restrict__ w_r2, f16* __restrict__ W2T) {
  int t = blockIdx.x * 256 + threadIdx.x;
  if (t >= HID * WNUM) return;
  int n = t >> 6, k = t & 63;
  W2T[n * 64 + k] = (f16)w_r2[k * WNUM + n];
}

// ---------------- node irrep norm (float4 vectorized) ----------------
extern "C" __global__ __launch_bounds__(256) void k_xnorm(
    const float* __restrict__ x, float* __restrict__ xnorm, int N) {
  int n = blockIdx.x * 256 + threadIdx.x;
  if (n >= N) return;
  const float4* xr = (const float4*)(x + (long long)n * 40);
  float4 u[10];
#pragma unroll
  for (int i = 0; i < 10; i++) u[i] = xr[i];
  const float* f = (const float*)u;
  float ss = 0.f, vs = 0.f;
#pragma unroll
  for (int i = 0; i < 16; i++) ss += f[i] * f[i];
#pragma unroll
  for (int i = 16; i < 40; i++) vs += f[i] * f[i];
  float sr = rsqrtf(ss * (1.0f / 16.0f) + EPSF);
  float vr = rsqrtf(vs * (1.0f / 8.0f) + EPSF);
  float o[40];
#pragma unroll
  for (int i = 0; i < 16; i++) o[i] = f[i] * sr;
#pragma unroll
  for (int i = 16; i < 40; i++) o[i] = f[i] * vr;
  float4* op = (float4*)(xnorm + (long long)n * 40);
#pragma unroll
  for (int i = 0; i < 10; i++) op[i] = ((const float4*)o)[i];
}

// ---------------- fused edge kernel ----------------
// block = 256 threads = 4 waves, 64 edges. Each wave owns 16 edges.
extern "C" __global__ __launch_bounds__(256) void k_edge(
    const float* __restrict__ xnorm, const int* __restrict__ esrc,
    const int* __restrict__ edst, const float* __restrict__ sh,
    const float* __restrict__ rbf, const float* __restrict__ elen,
    const float* __restrict__ w_r1, const float* __restrict__ b_r1,
    const float* __restrict__ w_g1, const float* __restrict__ b_g1,
    const float* __restrict__ w_g2, const float* __restrict__ b_g2,
    const float* __restrict__ b_r2, const f16* __restrict__ W2T,
    float* __restrict__ agg0, float* __restrict__ agg1,
    float* __restrict__ normb, int E) {
  __shared__ float s_rbf[64][NRBF + 1];   // padded: stride 9 kills 16-way conflicts
  __shared__ float s_shT[4][64];
  __shared__ int s_src[64];
  __shared__ int s_dst[64];
  __shared__ float s_ew[64];
  __shared__ float s_gp[64][5];           // padded: stride 5
  __shared__ float s_a0T[16][64];         // transposed: e fast -> conflict-free
  __shared__ float s_a1T[8][64];
  __shared__ float s_snT[16][64];
  __shared__ float s_vshT[24][64];
  __shared__ __align__(16) f16 s_H[64][64];
  __shared__ float s_br2[WNUM];

  const int t = threadIdx.x;
  const long long eb = (long long)blockIdx.x * 64;

  // ---- phase 0: cooperative staging ----
  {
    for (int i = t; i < 64 * NRBF; i += 256) {
      long long g = eb * NRBF + i;
      s_rbf[i >> 3][i & 7] = (g < (long long)E * NRBF) ? rbf[g] : 0.f;
    }
    {
      long long g = eb * 4 + t;
      float v = (g < (long long)E * 4) ? sh[g] : 0.f;
      s_shT[t & 3][t >> 2] = v;
    }
    for (int i = t; i < WNUM; i += 256) s_br2[i] = b_r2[i];
    if (t < 64) {
      long long g = eb + t;
      s_src[t] = (g < E) ? esrc[g] : 0;
      s_dst[t] = (g < E) ? edst[g] : 0;
    }
  }
  __syncthreads();

  // ---- phase A1: hidden layer H (f16), all 256 threads ----
  {
    int h = t & 63, grp = t >> 6;
    float wr[NRBF];
#pragma unroll
    for (int r = 0; r < NRBF; r++) wr[r] = w_r1[r * HID + h];
    float bh = b_r1[h];
    for (int u = 0; u < 16; u++) {
      int e = grp * 16 + u;
      float acc = bh;
#pragma unroll
      for (int r = 0; r < NRBF; r++) acc += s_rbf[e][r] * wr[r];
      s_H[e][h] = (f16)(acc * sigm(acc));
    }
  }

  // ---- phase A2: gathers, all 256 threads (4 per edge) ----
  {
    const int e = t >> 2, q = t & 3;
    const float* xr = xnorm + (long long)s_src[e] * 40;
    const float sh0 = s_shT[0][e];
    if (q < 2) {
      float4 u0 = ((const float4*)xr)[q * 2];
      float4 u1 = ((const float4*)xr)[q * 2 + 1];
      float vals[8] = {u0.x, u0.y, u0.z, u0.w, u1.x, u1.y, u1.z, u1.w};
      const int i0 = q * 8;
#pragma unroll
      for (int k = 0; k < 8; k++) {
        s_snT[i0 + k][e] = vals[k];
        s_a0T[i0 + k][e] = vals[k] * sh0;
      }
    } else {
      const float shx = s_shT[1][e], shy = s_shT[2][e], shz = s_shT[3][e];
      const float4* p = (const float4*)(xr + 16 + (q - 2) * 12);
      float4 u0 = p[0], u1 = p[1], u2 = p[2];
      float vals[12] = {u0.x, u0.y, u0.z, u0.w, u1.x, u1.y,
                        u1.z, u1.w, u2.x, u2.y, u2.z, u2.w};
      const int i0 = (q - 2) * 4;
#pragma unroll
      for (int k = 0; k < 4; k++) {
        float vx = vals[3 * k], vy = vals[3 * k + 1], vz = vals[3 * k + 2];
        s_a1T[i0 + k][e] = INV_SQRT3 * (vx * shx + vy * shy + vz * shz);
        s_vshT[(i0 + k) * 3 + 0][e] = vx * sh0;
        s_vshT[(i0 + k) * 3 + 1][e] = vy * sh0;
        s_vshT[(i0 + k) * 3 + 2][e] = vz * sh0;
      }
    }
  }

  // ---- phase A3: gate MLP partials, all 256 threads (4 per edge) ----
  {
    const int e = t & 63, qq = t >> 6;
    float rb[NRBF];
#pragma unroll
    for (int r = 0; r < NRBF; r++) rb[r] = s_rbf[e][r];
    float acc = 0.f;
#pragma unroll
    for (int kk = 0; kk < 16; kk++) {
      int k = qq * 16 + kk;  // wave-uniform -> scalar loads for w_g1/w_g2
      float tt = b_g1[k];
#pragma unroll
      for (int r = 0; r < NRBF; r++) tt += rb[r] * w_g1[r * HID + k];
      acc += tt * sigm(tt) * w_g2[k];
    }
    s_gp[e][qq] = acc;
  }
  __syncthreads();

  if (t < 64) {
    long long g = eb + t;
    float acc = s_gp[t][0] + s_gp[t][1] + s_gp[t][2] + s_gp[t][3] + b_g2[0];
    float ew = 0.f;
    if (g < E) {
      float len = elen[g];
      float cw = (len < CUTOFF) ? 0.5f * (__cosf(PI_OVER_CUT * len) + 1.0f) : 0.f;
      ew = cw * sigm(acc);
    }
    s_ew[t] = ew;
  }

  // ---- A-fragments (s_H is complete; barrier above covers it) ----
  const int lane = t & 63;
  const int wv = t >> 6;
  const int quad = lane >> 4;
  const int c = lane & 15;
  const int e0 = wv * 16;

  const f16x8 af0 = *(const f16x8*)&s_H[e0 + c][quad * 8];
  const f16x8 af1 = *(const f16x8*)&s_H[e0 + c][32 + quad * 8];

  __syncthreads();  // covers s_ew before epilogue reads it

  // ---- phase B: software-pipelined MFMA over 36 j-tiles ----
  float m0a[4] = {0.f, 0.f, 0.f, 0.f};
  float t3a[4] = {0.f, 0.f, 0.f, 0.f};
  float m1x[4] = {0.f, 0.f, 0.f, 0.f};
  float m1y[4] = {0.f, 0.f, 0.f, 0.f};
  float m1z[4] = {0.f, 0.f, 0.f, 0.f};

  const f16* wb = W2T + (long long)c * 64 + quad * 8;

  f16x8 rb0[3], rb1[3];
#pragma unroll
  for (int p = 0; p < 3; p++) {
    rb0[p] = *(const f16x8*)(wb + p * 1024);
    rb1[p] = *(const f16x8*)(wb + p * 1024 + 32);
  }

#pragma unroll
  for (int jt = 0; jt < 36; jt++) {
    const int s = jt % 3;
    f16x8 b0 = rb0[s], b1 = rb1[s];
    if (jt + 3 < 36) {
      rb0[s] = *(const f16x8*)(wb + (jt + 3) * 1024);
      rb1[s] = *(const f16x8*)(wb + (jt + 3) * 1024 + 32);
    }
    f32x4 C = {0.f, 0.f, 0.f, 0.f};
    C = __builtin_amdgcn_mfma_f32_16x16x32_f16(af0, b0, C, 0, 0, 0);
    C = __builtin_amdgcn_mfma_f32_16x16x32_f16(af1, b1, C, 0, 0, 0);
    const float bias = s_br2[jt * 16 + c];
    if (jt < 16) {
#pragma unroll
      for (int r = 0; r < 4; r++)
        m0a[r] += s_a0T[jt][e0 + quad * 4 + r] * (C[r] + bias);
    } else if (jt < 24) {
#pragma unroll
      for (int r = 0; r < 4; r++)
        m0a[r] += s_a1T[jt - 16][e0 + quad * 4 + r] * (C[r] + bias);
    } else if (jt < 32) {
      const int i = (jt - 24) * 2 + (c >> 3);
#pragma unroll
      for (int r = 0; r < 4; r++)
        t3a[r] += s_snT[i][e0 + quad * 4 + r] * (C[r] + bias);
    } else {
      const int i = (jt - 32) * 2 + (c >> 3);
#pragma unroll
      for (int r = 0; r < 4; r++) {
        const int e = e0 + quad * 4 + r;
        const float wvv = C[r] + bias;
        m1x[r] += s_vshT[3 * i + 0][e] * wvv;
        m1y[r] += s_vshT[3 * i + 1][e] * wvv;
        m1z[r] += s_vshT[3 * i + 2][e] * wvv;
      }
    }
  }

  // fold the two column-halves (c and c^8 share output j = c&7)
#pragma unroll
  for (int r = 0; r < 4; r++) {
    t3a[r] += __shfl_xor(t3a[r], 8, 64);
    m1x[r] += __shfl_xor(m1x[r], 8, 64);
    m1y[r] += __shfl_xor(m1y[r], 8, 64);
    m1z[r] += __shfl_xor(m1z[r], 8, 64);
  }

  // ---- epilogue: scale + atomic scatter ----
#pragma unroll
  for (int r = 0; r < 4; r++) {
    const int e = e0 + quad * 4 + r;
    const float ew = s_ew[e];
    const float sc = A_PATH * ew;
    const int dst = s_dst[e];
    atomicAdd(&agg0[(long long)dst * 16 + c], m0a[r] * sc);
    if (c < 8) {
      const float t3v = t3a[r] * sc;
      const float ox = t3v * s_shT[1][e] + m1x[r] * sc;
      const float oy = t3v * s_shT[2][e] + m1y[r] * sc;
      const float oz = t3v * s_shT[3][e] + m1z[r] * sc;
      const long long b = (long long)dst * 24 + c * 3;
      atomicAdd(&agg1[b], ox);
      atomicAdd(&agg1[b + 1], oy);
      atomicAdd(&agg1[b + 2], oz);
    } else if (c == 8) {
      atomicAdd(&normb[dst], ew);
    }
  }
}

// ---------------- final node kernel ----------------
extern "C" __global__ __launch_bounds__(256) void k_node(
    const float* __restrict__ x, const float* __restrict__ xnorm,
    const float* __restrict__ agg0, const float* __restrict__ agg1,
    const float* __restrict__ normb, const float* __restrict__ Wm_s,
    const float* __restrict__ Wm_v, const float* __restrict__ Wu_s,
    const float* __restrict__ Wu_v, const float* __restrict__ Ws_s,
    const float* __restrict__ Ws_v, const float* __restrict__ res_scale_p,
    float* __restrict__ out, int N) {
  __shared__ float sWms[16 * 24];
  __shared__ float sWmv[64];
  __shared__ float sWus[256];
  __shared__ float sWuv[64];
  __shared__ float sWss[256];
  __shared__ float sWsv[64];
  int t = threadIdx.x;
  for (int i = t; i < 384; i += 256) sWms[i] = Wm_s[i];
  for (int i = t; i < 64; i += 256) sWmv[i] = Wm_v[i];
  for (int i = t; i < 256; i += 256) sWus[i] = Wu_s[i];
  for (int i = t; i < 64; i += 256) sWuv[i] = Wu_v[i];
  for (int i = t; i < 256; i += 256) sWss[i] = Ws_s[i];
  for (int i = t; i < 64; i += 256) sWsv[i] = Ws_v[i];
  __syncthreads();
  int n = blockIdx.x * 256 + t;
  if (n >= N) return;

  float inv = 1.0f / fmaxf(normb[n], EPSF);
  float a0[16], a1[24];
  {
    const float4* p0 = (const float4*)(agg0 + (long long)n * 16);
#pragma unroll
    for (int i = 0; i < 4; i++) ((float4*)a0)[i] = p0[i];
    const float4* p1 = (const float4*)(agg1 + (long long)n * 24);
#pragma unroll
    for (int i = 0; i < 6; i++) ((float4*)a1)[i] = p1[i];
  }
#pragma unroll
  for (int i = 0; i < 16; i++) a0[i] *= inv;
#pragma unroll
  for (int i = 0; i < 24; i++) a1[i] *= inv;

  float scal[16], gate[8];
#pragma unroll
  for (int jj = 0; jj < 24; jj++) {
    float acc = 0.f;
#pragma unroll
    for (int i = 0; i < 16; i++) acc += a0[i] * sWms[i * 24 + jj];
    acc *= Q16;
    if (jj < 16) scal[jj] = acc * sigm(acc);
    else gate[jj - 16] = sigm(acc);
  }
  float vg[24];
#pragma unroll
  for (int j = 0; j < 8; j++) {
    float g = gate[j];
#pragma unroll
    for (int cc = 0; cc < 3; cc++) {
      float acc = 0.f;
#pragma unroll
      for (int i = 0; i < 8; i++) acc += a1[i * 3 + cc] * sWmv[i * 8 + j];
      vg[j * 3 + cc] = acc * Q8 * g;
    }
  }
  float xn[40], xo[40];
  {
    const float4* pn = (const float4*)(xnorm + (long long)n * 40);
    const float4* po = (const float4*)(x + (long long)n * 40);
#pragma unroll
    for (int i = 0; i < 10; i++) { ((float4*)xn)[i] = pn[i]; ((float4*)xo)[i] = po[i]; }
  }
  float rs = res_scale_p[0];
  float o[40];
#pragma unroll
  for (int j = 0; j < 16; j++) {
    float acc = 0.f, acc2 = 0.f;
#pragma unroll
    for (int i = 0; i < 16; i++) {
      acc += scal[i] * sWus[i * 16 + j];
      acc2 += xn[i] * sWss[i * 16 + j];
    }
    o[j] = xo[j] + rs * ((acc + acc2) * Q16);
  }
#pragma unroll
  for (int j = 0; j < 8; j++) {
#pragma unroll
    for (int cc = 0; cc < 3; cc++) {
      float acc = 0.f;
#pragma unroll
      for (int i = 0; i < 8; i++)
        acc += vg[i * 3 + cc] * sWuv[i * 8 + j] + xn[16 + i * 3 + cc] * sWsv[i * 8 + j];
      o[16 + j * 3 + cc] = xo[16 + j * 3 + cc] + rs * (acc * Q8);
    }
  }
  float4* op = (float4*)(out + (long long)n * 40);
#pragma unroll
  for (int i = 0; i < 10; i++) op[i] = ((const float4*)o)[i];
}

// ---------------- launch ----------------
extern "C" void kernel_launch(void* const* d_in, const int* in_sizes, int n_in,
                              void* d_out, int out_size, void* d_ws, size_t ws_size,
                              hipStream_t stream) {
  const float* x = (const float*)d_in[0];
  const int* esrc = (const int*)d_in[1];
  const int* edst = (const int*)d_in[2];
  const float* sh = (const float*)d_in[3];
  const float* rbf = (const float*)d_in[4];
  const float* elen = (const float*)d_in[5];
  const float* w_r1 = (const float*)d_in[6];
  const float* b_r1 = (const float*)d_in[7];
  const float* w_r2 = (const float*)d_in[8];
  const float* b_r2 = (const float*)d_in[9];
  const float* w_g1 = (const float*)d_in[10];
  const float* b_g1 = (const float*)d_in[11];
  const float* w_g2 = (const float*)d_in[12];
  const float* b_g2 = (const float*)d_in[13];
  const float* Wm_s = (const float*)d_in[14];
  const float* Wm_v = (const float*)d_in[15];
  const float* Wu_s = (const float*)d_in[16];
  const float* Wu_v = (const float*)d_in[17];
  const float* Ws_s = (const float*)d_in[18];
  const float* Ws_v = (const float*)d_in[19];
  const float* res_scale = (const float*)d_in[20];

  const int N = in_sizes[0] / 40;
  const int E = in_sizes[1];

  char* ws = (char*)d_ws;
  size_t off = 0;
  float* xnorm = (float*)(ws + off); off += (size_t)N * 40 * sizeof(float);
  off = (off + 255) & ~(size_t)255;
  float* agg0 = (float*)(ws + off); off += (size_t)N * 16 * sizeof(float);
  float* agg1 = (float*)(ws + off); off += (size_t)N * 24 * sizeof(float);
  float* normb = (float*)(ws + off); off += (size_t)N * sizeof(float);
  off = (off + 255) & ~(size_t)255;
  f16* W2T = (f16*)(ws + off); off += (size_t)WNUM * 64 * sizeof(f16);

  // zero accumulators (agg0, agg1, normb are contiguous)
  hipMemsetAsync(agg0, 0, (size_t)N * 41 * sizeof(float), stream);

  k_prep_w2t<<<(HID * WNUM + 255) / 256, 256, 0, stream>>>(w_r2, W2T);
  k_xnorm<<<(N + 255) / 256, 256, 0, stream>>>(x, xnorm, N);

  int nblk = (E + 63) / 64;
  k_edge<<<nblk, 256, 0, stream>>>(xnorm, esrc, edst, sh, rbf, elen, w_r1, b_r1,
                                   w_g1, b_g1, w_g2, b_g2, b_r2, W2T, agg0, agg1,
                                   normb, E);

  k_node<<<(N + 255) / 256, 256, 0, stream>>>(x, xnorm, agg0, agg1, normb, Wm_s,
                                              Wm_v, Wu_s, Wu_v, Ws_s, Ws_v,
                                              res_scale, (float*)d_out, N);
}

// Round 3
// 458.217 us; speedup vs baseline: 1.1627x; 1.1627x over previous
//
#include <hip/hip_runtime.h>
#include <cstdint>

#define MUL0 16
#define MUL1 8
#define NRBF 8
#define HID 64
#define WNUM 576
#define CUTOFF 5.0f
#define EPSF 1e-8f

#define INV_SQRT3 0.57735026918962576f
#define A_PATH    0.20412414523193154f   /* 1/sqrt(24) */
#define Q16       0.25f                  /* 1/sqrt(16) */
#define Q8        0.35355339059327373f   /* 1/sqrt(8)  */
#define PI_OVER_CUT 0.62831853071795865f /* pi/5 */

typedef _Float16 f16;
typedef _Float16 f16x8 __attribute__((ext_vector_type(8)));
typedef float f32x4 __attribute__((ext_vector_type(4)));

__device__ __forceinline__ float sigm(float x) { return 1.0f / (1.0f + __expf(-x)); }

// ---------------- prep: w_r2 (64 x 576 f32) -> W2T (576 x 64 f16) ----------------
extern "C" __global__ __launch_bounds__(256) void k_prep_w2t(
    const float* __restrict__ w_r2, f16* __restrict__ W2T) {
  int t = blockIdx.x * 256 + threadIdx.x;
  if (t >= HID * WNUM) return;
  int n = t >> 6, k = t & 63;
  W2T[n * 64 + k] = (f16)w_r2[k * WNUM + n];
}

// ---------------- node irrep norm (float4 vectorized) ----------------
extern "C" __global__ __launch_bounds__(256) void k_xnorm(
    const float* __restrict__ x, float* __restrict__ xnorm, int N) {
  int n = blockIdx.x * 256 + threadIdx.x;
  if (n >= N) return;
  const float4* xr = (const float4*)(x + (long long)n * 40);
  float4 u[10];
#pragma unroll
  for (int i = 0; i < 10; i++) u[i] = xr[i];
  const float* f = (const float*)u;
  float ss = 0.f, vs = 0.f;
#pragma unroll
  for (int i = 0; i < 16; i++) ss += f[i] * f[i];
#pragma unroll
  for (int i = 16; i < 40; i++) vs += f[i] * f[i];
  float sr = rsqrtf(ss * (1.0f / 16.0f) + EPSF);
  float vr = rsqrtf(vs * (1.0f / 8.0f) + EPSF);
  float o[40];
#pragma unroll
  for (int i = 0; i < 16; i++) o[i] = f[i] * sr;
#pragma unroll
  for (int i = 16; i < 40; i++) o[i] = f[i] * vr;
  float4* op = (float4*)(xnorm + (long long)n * 40);
#pragma unroll
  for (int i = 0; i < 10; i++) op[i] = ((const float4*)o)[i];
}

// ---------------- fused edge kernel ----------------
// block = 256 threads = 4 waves, 64 edges. Each wave owns 16 edges.
extern "C" __global__ __launch_bounds__(256) void k_edge(
    const float* __restrict__ xnorm, const int* __restrict__ esrc,
    const int* __restrict__ edst, const float* __restrict__ sh,
    const float* __restrict__ rbf, const float* __restrict__ elen,
    const float* __restrict__ w_r1, const float* __restrict__ b_r1,
    const float* __restrict__ w_g1, const float* __restrict__ b_g1,
    const float* __restrict__ w_g2, const float* __restrict__ b_g2,
    const float* __restrict__ b_r2, const f16* __restrict__ W2T,
    float* __restrict__ agg0, float* __restrict__ agg1,
    float* __restrict__ normb, int E) {
  __shared__ float s_rbf[64][12];        // stride 12: 16B-aligned rows for b128
  __shared__ float s_shT[4][64];
  __shared__ int s_dst[64];
  __shared__ float s_ew[64];
  __shared__ float s_gp[64][5];
  __shared__ float s_snT[16][64];        // raw s (sh0 factored into epilogue)
  __shared__ float s_a1T[8][64];
  __shared__ float s_vT[24][64];         // raw v (sh0 factored into epilogue)
  __shared__ __align__(16) f16 s_H[64][64];
  __shared__ float s_br2[WNUM];

  const int t = threadIdx.x;
  const long long eb = (long long)blockIdx.x * 64;

  // ---- gather issue: registers only, no barrier dependency. Latency hides
  //      behind phase-0 staging + A1 compute. ----
  const int e2 = t >> 2, q = t & 3;
  long long ge = eb + e2; if (ge >= E) ge = E - 1;
  const int src = esrc[ge];
  const float* xr = xnorm + (long long)src * 40;
  float4 g0, g1, g2, shv;
  if (q < 2) {
    g0 = ((const float4*)xr)[q * 2];
    g1 = ((const float4*)xr)[q * 2 + 1];
  } else {
    const float4* p = (const float4*)(xr + 16 + (q - 2) * 12);
    g0 = p[0]; g1 = p[1]; g2 = p[2];
    shv = ((const float4*)sh)[ge];
  }

  // ---- A1 weights into regs (global, independent of LDS) ----
  float wr[NRBF];
  const int h = t & 63;
#pragma unroll
  for (int r = 0; r < NRBF; r++) wr[r] = w_r1[r * HID + h];
  const float bh = b_r1[h];

  // ---- phase 0: stage LDS ----
  for (int i = t; i < 64 * NRBF; i += 256) {
    long long g = eb * NRBF + i;
    s_rbf[i >> 3][i & 7] = (g < (long long)E * NRBF) ? rbf[g] : 0.f;
  }
  {
    long long g = eb * 4 + t;
    s_shT[t & 3][t >> 2] = (g < (long long)E * 4) ? sh[g] : 0.f;
  }
  for (int i = t; i < WNUM; i += 256) s_br2[i] = b_r2[i];
  if (t < 64) {
    long long g = eb + t;
    s_dst[t] = (g < E) ? edst[g] : 0;
  }
  __syncthreads();

  // ---- A1: H = silu(rbf @ w_r1 + b) (broadcast b128 LDS reads) ----
  {
    const int grp = t >> 6;
#pragma unroll
    for (int u = 0; u < 16; u++) {
      const int e = grp * 16 + u;
      float4 ra = *(const float4*)&s_rbf[e][0];
      float4 rb = *(const float4*)&s_rbf[e][4];
      float acc = bh + ra.x * wr[0] + ra.y * wr[1] + ra.z * wr[2] + ra.w * wr[3] +
                  rb.x * wr[4] + rb.y * wr[5] + rb.z * wr[6] + rb.w * wr[7];
      s_H[e][h] = (f16)(acc * sigm(acc));
    }
  }

  // ---- A2: commit gathered values (first use of g* -> waitcnt lands here) ----
  if (q < 2) {
    float vals[8] = {g0.x, g0.y, g0.z, g0.w, g1.x, g1.y, g1.z, g1.w};
    const int i0 = q * 8;
#pragma unroll
    for (int k = 0; k < 8; k++) s_snT[i0 + k][e2] = vals[k];
  } else {
    float vals[12] = {g0.x, g0.y, g0.z, g0.w, g1.x, g1.y,
                      g1.z, g1.w, g2.x, g2.y, g2.z, g2.w};
    const int i0 = (q - 2) * 4;
#pragma unroll
    for (int k = 0; k < 4; k++) {
      float vx = vals[3 * k], vy = vals[3 * k + 1], vz = vals[3 * k + 2];
      s_a1T[i0 + k][e2] = INV_SQRT3 * (vx * shv.y + vy * shv.z + vz * shv.w);
      s_vT[(i0 + k) * 3 + 0][e2] = vx;
      s_vT[(i0 + k) * 3 + 1][e2] = vy;
      s_vT[(i0 + k) * 3 + 2][e2] = vz;
    }
  }

  // ---- A3: gate MLP partials (wave-uniform k -> scalar weight loads) ----
  {
    const int e = t & 63, qq = t >> 6;
    float rb[NRBF];
#pragma unroll
    for (int r = 0; r < NRBF; r++) rb[r] = s_rbf[e][r];
    float acc = 0.f;
#pragma unroll
    for (int kk = 0; kk < 16; kk++) {
      int k = qq * 16 + kk;
      float tt = b_g1[k];
#pragma unroll
      for (int r = 0; r < NRBF; r++) tt += rb[r] * w_g1[r * HID + k];
      acc += tt * sigm(tt) * w_g2[k];
    }
    s_gp[e][qq] = acc;
  }

  // ---- prefetch first two B tiles (global; independent of LDS) ----
  const int lane = t & 63;
  const int wv = t >> 6;
  const int quad = lane >> 4;
  const int c = lane & 15;
  const int e0 = wv * 16;
  const f16* wb = W2T + c * 64 + quad * 8;
  f16x8 rb0[2], rb1[2];
  rb0[0] = *(const f16x8*)(wb);
  rb1[0] = *(const f16x8*)(wb + 32);
  rb0[1] = *(const f16x8*)(wb + 1024);
  rb1[1] = *(const f16x8*)(wb + 1024 + 32);

  __syncthreads();

  // ---- ew finalize ----
  if (t < 64) {
    long long g = eb + t;
    float acc = s_gp[t][0] + s_gp[t][1] + s_gp[t][2] + s_gp[t][3] + b_g2[0];
    float ew = 0.f;
    if (g < E) {
      float len = elen[g];
      float cw = (len < CUTOFF) ? 0.5f * (__cosf(PI_OVER_CUT * len) + 1.0f) : 0.f;
      ew = cw * sigm(acc);
    }
    s_ew[t] = ew;
  }

  // ---- A-fragments (s_H complete per barrier above) ----
  const f16x8 af0 = *(const f16x8*)&s_H[e0 + c][quad * 8];
  const f16x8 af1 = *(const f16x8*)&s_H[e0 + c][32 + quad * 8];

  __syncthreads();  // covers s_ew + A2/A3 LDS writes

  // ---- phase B: depth-2 double-buffered MFMA over 36 j-tiles ----
  float m0s[4] = {0.f, 0.f, 0.f, 0.f};
  float m0v[4] = {0.f, 0.f, 0.f, 0.f};
  float t3a[4] = {0.f, 0.f, 0.f, 0.f};
  float m1x[4] = {0.f, 0.f, 0.f, 0.f};
  float m1y[4] = {0.f, 0.f, 0.f, 0.f};
  float m1z[4] = {0.f, 0.f, 0.f, 0.f};

#pragma unroll 2
  for (int jt = 0; jt < 36; jt++) {
    const int s = jt & 1;
    f16x8 b0 = rb0[s], b1 = rb1[s];
    if (jt + 2 < 36) {
      rb0[s] = *(const f16x8*)(wb + (jt + 2) * 1024);
      rb1[s] = *(const f16x8*)(wb + (jt + 2) * 1024 + 32);
    }
    f32x4 C = {0.f, 0.f, 0.f, 0.f};
    C = __builtin_amdgcn_mfma_f32_16x16x32_f16(af0, b0, C, 0, 0, 0);
    C = __builtin_amdgcn_mfma_f32_16x16x32_f16(af1, b1, C, 0, 0, 0);
    const float bias = s_br2[jt * 16 + c];
    if (jt < 16) {
      const f32x4 sv = *(const f32x4*)&s_snT[jt][e0 + quad * 4];
#pragma unroll
      for (int r = 0; r < 4; r++) m0s[r] += sv[r] * (C[r] + bias);
    } else if (jt < 24) {
      const f32x4 av = *(const f32x4*)&s_a1T[jt - 16][e0 + quad * 4];
#pragma unroll
      for (int r = 0; r < 4; r++) m0v[r] += av[r] * (C[r] + bias);
    } else if (jt < 32) {
      const int i = (jt - 24) * 2 + (c >> 3);
      const f32x4 sv = *(const f32x4*)&s_snT[i][e0 + quad * 4];
#pragma unroll
      for (int r = 0; r < 4; r++) t3a[r] += sv[r] * (C[r] + bias);
    } else {
      const int i = (jt - 32) * 2 + (c >> 3);
      const f32x4 vx4 = *(const f32x4*)&s_vT[3 * i + 0][e0 + quad * 4];
      const f32x4 vy4 = *(const f32x4*)&s_vT[3 * i + 1][e0 + quad * 4];
      const f32x4 vz4 = *(const f32x4*)&s_vT[3 * i + 2][e0 + quad * 4];
#pragma unroll
      for (int r = 0; r < 4; r++) {
        const float wvv = C[r] + bias;
        m1x[r] += vx4[r] * wvv;
        m1y[r] += vy4[r] * wvv;
        m1z[r] += vz4[r] * wvv;
      }
    }
  }

  // fold the two column-halves (c and c^8 share output j = c&7)
#pragma unroll
  for (int r = 0; r < 4; r++) {
    t3a[r] += __shfl_xor(t3a[r], 8, 64);
    m1x[r] += __shfl_xor(m1x[r], 8, 64);
    m1y[r] += __shfl_xor(m1y[r], 8, 64);
    m1z[r] += __shfl_xor(m1z[r], 8, 64);
  }

  // ---- epilogue: scale + atomic scatter (sh0 applied here) ----
#pragma unroll
  for (int r = 0; r < 4; r++) {
    const int e = e0 + quad * 4 + r;
    const float ew = s_ew[e];
    const float sc = A_PATH * ew;
    const float sh0 = s_shT[0][e];
    const int dst = s_dst[e];
    atomicAdd(&agg0[(long long)dst * 16 + c], (sh0 * m0s[r] + m0v[r]) * sc);
    if (c < 8) {
      const float ox = sc * (t3a[r] * s_shT[1][e] + m1x[r] * sh0);
      const float oy = sc * (t3a[r] * s_shT[2][e] + m1y[r] * sh0);
      const float oz = sc * (t3a[r] * s_shT[3][e] + m1z[r] * sh0);
      const long long b = (long long)dst * 24 + c * 3;
      atomicAdd(&agg1[b], ox);
      atomicAdd(&agg1[b + 1], oy);
      atomicAdd(&agg1[b + 2], oz);
    } else if (c == 8) {
      atomicAdd(&normb[dst], ew);
    }
  }
}

// ---------------- final node kernel ----------------
extern "C" __global__ __launch_bounds__(256) void k_node(
    const float* __restrict__ x, const float* __restrict__ xnorm,
    const float* __restrict__ agg0, const float* __restrict__ agg1,
    const float* __restrict__ normb, const float* __restrict__ Wm_s,
    const float* __restrict__ Wm_v, const float* __restrict__ Wu_s,
    const float* __restrict__ Wu_v, const float* __restrict__ Ws_s,
    const float* __restrict__ Ws_v, const float* __restrict__ res_scale_p,
    float* __restrict__ out, int N) {
  __shared__ float sWms[16 * 24];
  __shared__ float sWmv[64];
  __shared__ float sWus[256];
  __shared__ float sWuv[64];
  __shared__ float sWss[256];
  __shared__ float sWsv[64];
  int t = threadIdx.x;
  for (int i = t; i < 384; i += 256) sWms[i] = Wm_s[i];
  for (int i = t; i < 64; i += 256) sWmv[i] = Wm_v[i];
  for (int i = t; i < 256; i += 256) sWus[i] = Wu_s[i];
  for (int i = t; i < 64; i += 256) sWuv[i] = Wu_v[i];
  for (int i = t; i < 256; i += 256) sWss[i] = Ws_s[i];
  for (int i = t; i < 64; i += 256) sWsv[i] = Ws_v[i];
  __syncthreads();
  int n = blockIdx.x * 256 + t;
  if (n >= N) return;

  float inv = 1.0f / fmaxf(normb[n], EPSF);
  float a0[16], a1[24];
  {
    const float4* p0 = (const float4*)(agg0 + (long long)n * 16);
#pragma unroll
    for (int i = 0; i < 4; i++) ((float4*)a0)[i] = p0[i];
    const float4* p1 = (const float4*)(agg1 + (long long)n * 24);
#pragma unroll
    for (int i = 0; i < 6; i++) ((float4*)a1)[i] = p1[i];
  }
#pragma unroll
  for (int i = 0; i < 16; i++) a0[i] *= inv;
#pragma unroll
  for (int i = 0; i < 24; i++) a1[i] *= inv;

  float scal[16], gate[8];
#pragma unroll
  for (int jj = 0; jj < 24; jj++) {
    float acc = 0.f;
#pragma unroll
    for (int i = 0; i < 16; i++) acc += a0[i] * sWms[i * 24 + jj];
    acc *= Q16;
    if (jj < 16) scal[jj] = acc * sigm(acc);
    else gate[jj - 16] = sigm(acc);
  }
  float vg[24];
#pragma unroll
  for (int j = 0; j < 8; j++) {
    float g = gate[j];
#pragma unroll
    for (int cc = 0; cc < 3; cc++) {
      float acc = 0.f;
#pragma unroll
      for (int i = 0; i < 8; i++) acc += a1[i * 3 + cc] * sWmv[i * 8 + j];
      vg[j * 3 + cc] = acc * Q8 * g;
    }
  }
  float xn[40], xo[40];
  {
    const float4* pn = (const float4*)(xnorm + (long long)n * 40);
    const float4* po = (const float4*)(x + (long long)n * 40);
#pragma unroll
    for (int i = 0; i < 10; i++) { ((float4*)xn)[i] = pn[i]; ((float4*)xo)[i] = po[i]; }
  }
  float rs = res_scale_p[0];
  float o[40];
#pragma unroll
  for (int j = 0; j < 16; j++) {
    float acc = 0.f, acc2 = 0.f;
#pragma unroll
    for (int i = 0; i < 16; i++) {
      acc += scal[i] * sWus[i * 16 + j];
      acc2 += xn[i] * sWss[i * 16 + j];
    }
    o[j] = xo[j] + rs * ((acc + acc2) * Q16);
  }
#pragma unroll
  for (int j = 0; j < 8; j++) {
#pragma unroll
    for (int cc = 0; cc < 3; cc++) {
      float acc = 0.f;
#pragma unroll
      for (int i = 0; i < 8; i++)
        acc += vg[i * 3 + cc] * sWuv[i * 8 + j] + xn[16 + i * 3 + cc] * sWsv[i * 8 + j];
      o[16 + j * 3 + cc] = xo[16 + j * 3 + cc] + rs * (acc * Q8);
    }
  }
  float4* op = (float4*)(out + (long long)n * 40);
#pragma unroll
  for (int i = 0; i < 10; i++) op[i] = ((const float4*)o)[i];
}

// ---------------- launch ----------------
extern "C" void kernel_launch(void* const* d_in, const int* in_sizes, int n_in,
                              void* d_out, int out_size, void* d_ws, size_t ws_size,
                              hipStream_t stream) {
  const float* x = (const float*)d_in[0];
  const int* esrc = (const int*)d_in[1];
  const int* edst = (const int*)d_in[2];
  const float* sh = (const float*)d_in[3];
  const float* rbf = (const float*)d_in[4];
  const float* elen = (const float*)d_in[5];
  const float* w_r1 = (const float*)d_in[6];
  const float* b_r1 = (const float*)d_in[7];
  const float* w_r2 = (const float*)d_in[8];
  const float* b_r2 = (const float*)d_in[9];
  const float* w_g1 = (const float*)d_in[10];
  const float* b_g1 = (const float*)d_in[11];
  const float* w_g2 = (const float*)d_in[12];
  const float* b_g2 = (const float*)d_in[13];
  const float* Wm_s = (const float*)d_in[14];
  const float* Wm_v = (const float*)d_in[15];
  const float* Wu_s = (const float*)d_in[16];
  const float* Wu_v = (const float*)d_in[17];
  const float* Ws_s = (const float*)d_in[18];
  const float* Ws_v = (const float*)d_in[19];
  const float* res_scale = (const float*)d_in[20];

  const int N = in_sizes[0] / 40;
  const int E = in_sizes[1];

  char* ws = (char*)d_ws;
  size_t off = 0;
  float* xnorm = (float*)(ws + off); off += (size_t)N * 40 * sizeof(float);
  off = (off + 255) & ~(size_t)255;
  float* agg0 = (float*)(ws + off); off += (size_t)N * 16 * sizeof(float);
  float* agg1 = (float*)(ws + off); off += (size_t)N * 24 * sizeof(float);
  float* normb = (float*)(ws + off); off += (size_t)N * sizeof(float);
  off = (off + 255) & ~(size_t)255;
  f16* W2T = (f16*)(ws + off); off += (size_t)WNUM * 64 * sizeof(f16);

  // zero accumulators (agg0, agg1, normb are contiguous)
  hipMemsetAsync(agg0, 0, (size_t)N * 41 * sizeof(float), stream);

  k_prep_w2t<<<(HID * WNUM + 255) / 256, 256, 0, stream>>>(w_r2, W2T);
  k_xnorm<<<(N + 255) / 256, 256, 0, stream>>>(x, xnorm, N);

  int nblk = (E + 63) / 64;
  k_edge<<<nblk, 256, 0, stream>>>(xnorm, esrc, edst, sh, rbf, elen, w_r1, b_r1,
                                   w_g1, b_g1, w_g2, b_g2, b_r2, W2T, agg0, agg1,
                                   normb, E);

  k_node<<<(N + 255) / 256, 256, 0, stream>>>(x, xnorm, agg0, agg1, normb, Wm_s,
                                              Wm_v, Wu_s, Wu_v, Ws_s, Ws_v,
                                              res_scale, (float*)d_out, N);
}